// Round 3
// baseline (287.175 us; speedup 1.0000x reference)
//
#include <hip/hip_runtime.h>

// y[i] = (x[i]*W0 >= x[i]*W1) ? -1.0f : +1.0f
// (argmax over [x*W0, x*W1] with first-max tie-break, then 2*idx-1).
// Both products computed and compared (not x*(W0-W1) vs 0) to stay
// bit-exact with the reference on round-to-same-float near-ties.
//
// Memory-bound streaming op. 2x 16B vectors per thread for MLP; nontemporal
// stores keep the write-once output out of L2/L3 so L3 can serve the input.

typedef float vf4 __attribute__((ext_vector_type(4)));  // native vector: OK for nontemporal builtins

__global__ __launch_bounds__(256) void metaconv_sign8(
    const vf4* __restrict__ x4,
    const float* __restrict__ W,
    vf4* __restrict__ out4,
    int n4)
{
    int t = blockIdx.x * blockDim.x + threadIdx.x;
    int i0 = 2 * t;
    float w0 = W[0];   // wave-uniform -> s_load
    float w1 = W[1];
    if (i0 + 1 < n4) {
        // Issue both loads before any use: 2 outstanding dwordx4 per lane.
        vf4 a = x4[i0];
        vf4 b = x4[i0 + 1];
        vf4 ra, rb;
        ra.x = (a.x * w0 >= a.x * w1) ? -1.0f : 1.0f;
        ra.y = (a.y * w0 >= a.y * w1) ? -1.0f : 1.0f;
        ra.z = (a.z * w0 >= a.z * w1) ? -1.0f : 1.0f;
        ra.w = (a.w * w0 >= a.w * w1) ? -1.0f : 1.0f;
        rb.x = (b.x * w0 >= b.x * w1) ? -1.0f : 1.0f;
        rb.y = (b.y * w0 >= b.y * w1) ? -1.0f : 1.0f;
        rb.z = (b.z * w0 >= b.z * w1) ? -1.0f : 1.0f;
        rb.w = (b.w * w0 >= b.w * w1) ? -1.0f : 1.0f;
        __builtin_nontemporal_store(ra, &out4[i0]);
        __builtin_nontemporal_store(rb, &out4[i0 + 1]);
    } else if (i0 < n4) {
        vf4 a = x4[i0];
        vf4 ra;
        ra.x = (a.x * w0 >= a.x * w1) ? -1.0f : 1.0f;
        ra.y = (a.y * w0 >= a.y * w1) ? -1.0f : 1.0f;
        ra.z = (a.z * w0 >= a.z * w1) ? -1.0f : 1.0f;
        ra.w = (a.w * w0 >= a.w * w1) ? -1.0f : 1.0f;
        __builtin_nontemporal_store(ra, &out4[i0]);
    }
}

// Scalar tail for n not divisible by 4 (not hit for this problem's N).
__global__ void metaconv_sign_tail(
    const float* __restrict__ x,
    const float* __restrict__ W,
    float* __restrict__ out,
    int start, int n)
{
    int i = start + blockIdx.x * blockDim.x + threadIdx.x;
    float w0 = W[0];
    float w1 = W[1];
    if (i < n) {
        float v = x[i];
        out[i] = (v * w0 >= v * w1) ? -1.0f : 1.0f;
    }
}

extern "C" void kernel_launch(void* const* d_in, const int* in_sizes, int n_in,
                              void* d_out, int out_size, void* d_ws, size_t ws_size,
                              hipStream_t stream)
{
    const float* x = (const float*)d_in[0];
    const float* W = (const float*)d_in[1];
    float* out = (float*)d_out;

    int n = in_sizes[0];          // 2048*2048*3*3 = 37,748,736
    int n4 = n >> 2;              // float4 count
    int rem = n & 3;

    if (n4 > 0) {
        const int block = 256;
        int threads_needed = (n4 + 1) / 2;      // 2 vf4 per thread
        int grid = (threads_needed + block - 1) / block;
        metaconv_sign8<<<grid, block, 0, stream>>>(
            (const vf4*)x, W, (vf4*)out, n4);
    }
    if (rem > 0) {
        metaconv_sign_tail<<<1, 64, 0, stream>>>(x, W, out, n4 << 2, n);
    }
}

// Round 4
// 255.376 us; speedup vs baseline: 1.1245x; 1.1245x over previous
//
#include <hip/hip_runtime.h>

// y[i] = (x[i]*W0 >= x[i]*W1) ? -1.0f : +1.0f
// (argmax over [x*W0, x*W1] with first-max tie-break, then 2*idx-1).
// Both products computed and compared (not x*(W0-W1) vs 0) to stay
// bit-exact with the reference on round-to-same-float near-ties.
//
// Memory-bound streaming op. 2 float4 per thread, BLOCK-STRIDED so each
// load/store instruction is a contiguous 64-lane x 16B = 1KB transaction.
// (R3 lesson: interleaved per-thread pairs make every instruction strided
// -> 1.6x write amplification with nt stores, 2.7 TB/s. Normal stores:
// the harness's fill kernels sustain 6.6 TB/s with them.)

typedef float vf4 __attribute__((ext_vector_type(4)));

__global__ __launch_bounds__(256) void metaconv_sign8(
    const vf4* __restrict__ x4,
    const float* __restrict__ W,
    vf4* __restrict__ out4,
    int n4)
{
    // Each block owns a contiguous chunk of 2*256 float4s.
    int base = blockIdx.x * (2 * 256) + threadIdx.x;
    int i0 = base;          // lanes 0..255 -> consecutive float4s (coalesced)
    int i1 = base + 256;    // second coalesced chunk, independent load
    float w0 = W[0];        // wave-uniform -> s_load
    float w1 = W[1];

    if (i1 < n4) {
        // Both loads issued back-to-back: 2 outstanding dwordx4 per lane.
        vf4 a = x4[i0];
        vf4 b = x4[i1];
        vf4 ra, rb;
        ra.x = (a.x * w0 >= a.x * w1) ? -1.0f : 1.0f;
        ra.y = (a.y * w0 >= a.y * w1) ? -1.0f : 1.0f;
        ra.z = (a.z * w0 >= a.z * w1) ? -1.0f : 1.0f;
        ra.w = (a.w * w0 >= a.w * w1) ? -1.0f : 1.0f;
        rb.x = (b.x * w0 >= b.x * w1) ? -1.0f : 1.0f;
        rb.y = (b.y * w0 >= b.y * w1) ? -1.0f : 1.0f;
        rb.z = (b.z * w0 >= b.z * w1) ? -1.0f : 1.0f;
        rb.w = (b.w * w0 >= b.w * w1) ? -1.0f : 1.0f;
        out4[i0] = ra;
        out4[i1] = rb;
    } else if (i0 < n4) {
        vf4 a = x4[i0];
        vf4 ra;
        ra.x = (a.x * w0 >= a.x * w1) ? -1.0f : 1.0f;
        ra.y = (a.y * w0 >= a.y * w1) ? -1.0f : 1.0f;
        ra.z = (a.z * w0 >= a.z * w1) ? -1.0f : 1.0f;
        ra.w = (a.w * w0 >= a.w * w1) ? -1.0f : 1.0f;
        out4[i0] = ra;
    }
}

// Scalar tail for n not divisible by 4 (not hit for this problem's N).
__global__ void metaconv_sign_tail(
    const float* __restrict__ x,
    const float* __restrict__ W,
    float* __restrict__ out,
    int start, int n)
{
    int i = start + blockIdx.x * blockDim.x + threadIdx.x;
    float w0 = W[0];
    float w1 = W[1];
    if (i < n) {
        float v = x[i];
        out[i] = (v * w0 >= v * w1) ? -1.0f : 1.0f;
    }
}

extern "C" void kernel_launch(void* const* d_in, const int* in_sizes, int n_in,
                              void* d_out, int out_size, void* d_ws, size_t ws_size,
                              hipStream_t stream)
{
    const float* x = (const float*)d_in[0];
    const float* W = (const float*)d_in[1];
    float* out = (float*)d_out;

    int n = in_sizes[0];          // 2048*2048*3*3 = 37,748,736
    int n4 = n >> 2;              // float4 count
    int rem = n & 3;

    if (n4 > 0) {
        const int block = 256;
        const int per_block = 2 * block;   // 2 float4 per thread
        int grid = (n4 + per_block - 1) / per_block;
        metaconv_sign8<<<grid, block, 0, stream>>>(
            (const vf4*)x, W, (vf4*)out, n4);
    }
    if (rem > 0) {
        metaconv_sign_tail<<<1, 64, 0, stream>>>(x, W, out, n4 << 2, n);
    }
}

// Round 5
// 249.404 us; speedup vs baseline: 1.1514x; 1.0239x over previous
//
#include <hip/hip_runtime.h>

// y[i] = (x[i]*W0 >= x[i]*W1) ? -1.0f : +1.0f
// (argmax over [x*W0, x*W1] with first-max tie-break, then 2*idx-1).
// Both products computed and compared to stay bit-exact with the reference.
//
// R1 structure (1 float4/thread, fully coalesced — proven ~77 us) plus
// nontemporal stores: output is write-once, and keeping it OUT of L3 stops
// it evicting the L3-resident input (preloaded by the harness's d_in
// restore copy; R3 counters showed FETCH=74MB < 151MB input = free L3 hits).
// R3's nt regression was confounded by strided stores (partial-line writes);
// here every store instruction covers full 64B lines.

typedef float vf4 __attribute__((ext_vector_type(4)));

__global__ __launch_bounds__(256) void metaconv_sign4(
    const vf4* __restrict__ x4,
    const float* __restrict__ W,
    vf4* __restrict__ out4,
    int n4)
{
    int i = blockIdx.x * blockDim.x + threadIdx.x;
    float w0 = W[0];   // wave-uniform -> s_load
    float w1 = W[1];
    if (i < n4) {
        vf4 v = x4[i];          // normal load: wants L3 hits
        vf4 r;
        r.x = (v.x * w0 >= v.x * w1) ? -1.0f : 1.0f;
        r.y = (v.y * w0 >= v.y * w1) ? -1.0f : 1.0f;
        r.z = (v.z * w0 >= v.z * w1) ? -1.0f : 1.0f;
        r.w = (v.w * w0 >= v.w * w1) ? -1.0f : 1.0f;
        __builtin_nontemporal_store(r, &out4[i]);   // full-line, coalesced
    }
}

// Scalar tail for n not divisible by 4 (not hit for this problem's N).
__global__ void metaconv_sign_tail(
    const float* __restrict__ x,
    const float* __restrict__ W,
    float* __restrict__ out,
    int start, int n)
{
    int i = start + blockIdx.x * blockDim.x + threadIdx.x;
    float w0 = W[0];
    float w1 = W[1];
    if (i < n) {
        float v = x[i];
        out[i] = (v * w0 >= v * w1) ? -1.0f : 1.0f;
    }
}

extern "C" void kernel_launch(void* const* d_in, const int* in_sizes, int n_in,
                              void* d_out, int out_size, void* d_ws, size_t ws_size,
                              hipStream_t stream)
{
    const float* x = (const float*)d_in[0];
    const float* W = (const float*)d_in[1];
    float* out = (float*)d_out;

    int n = in_sizes[0];          // 2048*2048*3*3 = 37,748,736
    int n4 = n >> 2;              // float4 count
    int rem = n & 3;

    if (n4 > 0) {
        const int block = 256;
        int grid = (n4 + block - 1) / block;
        metaconv_sign4<<<grid, block, 0, stream>>>(
            (const vf4*)x, W, (vf4*)out, n4);
    }
    if (rem > 0) {
        metaconv_sign_tail<<<1, 64, 0, stream>>>(x, W, out, n4 << 2, n);
    }
}